// Round 10
// baseline (194.735 us; speedup 1.0000x reference)
//
#include <hip/hip_runtime.h>

typedef unsigned short u16;
typedef unsigned int   u32;

typedef short short8 __attribute__((ext_vector_type(8)));
typedef float floatx4 __attribute__((ext_vector_type(4)));

#define CDIM 128
#define K_NEG_LOG2E -1.4426950408889634f
#define CNT_SCALE 16777216.0   // 2^24: packs (sum, count) into one f64

// LDS weight tile: 128 rows x 136 u16 (272 B stride = 17*16 B).
#define WLDS_STRIDE 136
#define PACK_BLOCKS 512

__device__ __forceinline__ float bf2f_lo(u32 h) {
    union { u32 u; float f; } v; v.u = h << 16; return v.f;
}
__device__ __forceinline__ float bf2f_hi(u32 h) {
    union { u32 u; float f; } v; v.u = h & 0xffff0000u; return v.f;
}
__device__ __forceinline__ u16 f2bf(float f) {
    union { float f; u32 u; } v; v.f = f;
    u32 u = v.u;
    return (u16)((u + 0x7FFFu + ((u >> 16) & 1u)) >> 16);  // RNE
}
__device__ __forceinline__ float sig_std(float x) {
    return __builtin_amdgcn_rcpf(1.0f + __builtin_amdgcn_exp2f(x * K_NEG_LOG2E));
}

// One wave computes a 16-row tile from the LDS weight tile; stores
// exp2(proj + bias) in bf16.
__device__ __forceinline__ void proj_tile16_lds(
    const float* __restrict__ X, const u16* __restrict__ wlds,
    const float* __restrict__ bias, u16* __restrict__ out,
    int nrows, int ostride, int ooff, int row0, int lane)
{
    const int m = lane & 15;   // A-row / B-col / D-col
    const int g = lane >> 4;   // k-quad

    short8 a[4];
    {
        int arow = row0 + m;
        if (arow >= nrows) arow = nrows - 1;   // clamp; stores masked below
        const float* xrow = X + (size_t)arow * CDIM;
#pragma unroll
        for (int s = 0; s < 4; ++s) {
            float4 f0 = *(const float4*)(xrow + s * 32 + g * 8);
            float4 f1 = *(const float4*)(xrow + s * 32 + g * 8 + 4);
            a[s][0] = (short)f2bf(f0.x); a[s][1] = (short)f2bf(f0.y);
            a[s][2] = (short)f2bf(f0.z); a[s][3] = (short)f2bf(f0.w);
            a[s][4] = (short)f2bf(f1.x); a[s][5] = (short)f2bf(f1.y);
            a[s][6] = (short)f2bf(f1.z); a[s][7] = (short)f2bf(f1.w);
        }
    }

#pragma unroll
    for (int ct = 0; ct < 8; ++ct) {
        const u16* wrow = wlds + (size_t)(ct * 16 + m) * WLDS_STRIDE;
        floatx4 acc = {0.f, 0.f, 0.f, 0.f};
#pragma unroll
        for (int s = 0; s < 4; ++s) {
            short8 b = *(const short8*)(wrow + s * 32 + g * 8);
            acc = __builtin_amdgcn_mfma_f32_16x16x32_bf16(a[s], b, acc, 0, 0, 0);
        }
        const int col = ct * 16 + m;           // D: col = lane&15
        const float badd = bias ? bias[col] * K_NEG_LOG2E : 0.f;
#pragma unroll
        for (int i = 0; i < 4; ++i) {
            int r = row0 + g * 4 + i;          // D: row = (lane>>4)*4 + reg
            if (r < nrows)
                out[(size_t)r * ostride + ooff + col] =
                    f2bf(__builtin_amdgcn_exp2f(acc[i] + badd));
        }
    }
}

// ONE launch replacing prep+proj4. Block roles:
//   [0, PBtot): projection blocks (convert W -> pre-scaled bf16 LDS tile,
//     then project 64 rows).
//   [PBtot, PBtot+PACK_BLOCKS): zero f64 accumulators + pack edge indices.
__global__ __launch_bounds__(256) void fused_prep_proj(
    const float* __restrict__ stu_x, const float* __restrict__ item_x,
    const float* __restrict__ conc_x,
    const float* __restrict__ Wstu, const float* __restrict__ Witem,
    const float* __restrict__ b_stu, const float* __restrict__ b_item,
    u16* __restrict__ stu_p, u16* __restrict__ item_p, u16* __restrict__ conc_cat,
    float4* __restrict__ zero4, int nZero4,
    const int* __restrict__ stu_track, const int* __restrict__ item_index,
    const int* __restrict__ conc_index, const int* __restrict__ mean_index,
    int4* __restrict__ idx4, int E,
    int NS, int NI, int NC)
{
    __shared__ u16 wlds[128 * WLDS_STRIDE];

    const int PB0 = (NS + 63) / 64, PB1 = (NI + 63) / 64, PB2 = (NC + 63) / 64;
    const int PBtot = PB0 + PB1 + 2 * PB2;
    int b = blockIdx.x;

    if (b >= PBtot) {
        // ---- pack/zero role ----
        const int tid = (b - PBtot) * 256 + threadIdx.x;
        const int stride = PACK_BLOCKS * 256;
        const float4 z = {0.f, 0.f, 0.f, 0.f};
        for (int i = tid; i < nZero4; i += stride) zero4[i] = z;
        for (int e = tid; e < E; e += stride) {
            int4 t;
            t.x = stu_track[e]  << 8;   // 256 B rows
            t.y = item_index[e] << 8;   // 256 B rows
            t.z = conc_index[e] << 9;   // 512 B rows (cat)
            t.w = mean_index[e] << 3;   // f64 slots
            idx4[e] = t;
        }
        return;
    }

    // ---- projection role: segment select (block-uniform) ----
    const float* X; const float* Wsel; const float* bias;
    u16* out; int nrows, ostride, ooff, base;
    if (b < PB0)      { X = stu_x;  Wsel = Wstu;  bias = nullptr; out = stu_p;
                        nrows = NS; ostride = 128; ooff = 0;   base = b * 64; }
    else if ((b -= PB0) < PB1)
                      { X = item_x; Wsel = Witem; bias = nullptr; out = item_p;
                        nrows = NI; ostride = 128; ooff = 0;   base = b * 64; }
    else if ((b -= PB1) < PB2)
                      { X = conc_x; Wsel = Wstu;  bias = b_stu;  out = conc_cat;
                        nrows = NC; ostride = 256; ooff = 0;   base = b * 64; }
    else              { b -= PB2;
                        X = conc_x; Wsel = Witem; bias = b_item; out = conc_cat;
                        nrows = NC; ostride = 256; ooff = 128; base = b * 64; }

    // convert this block's W (f32 -> pre-scaled bf16) into LDS
    {
        const int t   = threadIdx.x;
        const int col = t >> 1;
        const int k0  = (t & 1) * 64;
        const float4* src = (const float4*)(Wsel + col * 128 + k0);
        u32* dst = (u32*)(wlds + col * WLDS_STRIDE + k0);
#pragma unroll
        for (int i = 0; i < 16; ++i) {
            float4 f = src[i];
            dst[2 * i]     = (u32)f2bf(f.x * K_NEG_LOG2E) |
                             ((u32)f2bf(f.y * K_NEG_LOG2E) << 16);
            dst[2 * i + 1] = (u32)f2bf(f.z * K_NEG_LOG2E) |
                             ((u32)f2bf(f.w * K_NEG_LOG2E) << 16);
        }
    }
    __syncthreads();

    const int lane = threadIdx.x & 63;
    const int row0 = base + (threadIdx.x >> 6) * 16;
    if (row0 < nrows)
        proj_tile16_lds(X, wlds, bias, out, nrows, ostride, ooff, row0, lane);
}

// 16 lanes per edge, 4 edges per wave. bf16 tables. Depth-2 stu/item,
// depth-1 conc, depth-3 idx issued FIRST (proven R8 structure, edge 70.2 us).
// This round's single change: grid 4096 -> 2048 blocks. 16384 waves at
// nQuads=62500 gave only ~3.8 steps/wave against a 3-deep prologue (~half
// of wave life was pipeline prime, 2 dispatch rounds/CU); 2048 blocks =
// exactly 8 resident blocks/CU, one round, 7.6 steps/wave.
__global__ __launch_bounds__(256) void edge_kernel(
    const u16* __restrict__ stu_p, const u16* __restrict__ item_p,
    const u16* __restrict__ conc_cat,
    const int4* __restrict__ idx4,     // byte offsets {stu, item, conc, mean}
    const float* __restrict__ w_pred,
    double* __restrict__ sc, int E)
{
    const int lane = threadIdx.x & 63;
    const int sub  = lane & 15;      // position within edge
    const int g    = lane >> 4;      // edge within quad
    const int waveId = (int)((blockIdx.x * blockDim.x + threadIdx.x) >> 6);
    const int S      = (int)((gridDim.x * blockDim.x) >> 6);   // wave stride

    const float4 wA = ((const float4*)w_pred)[sub * 2];
    const float4 wB = ((const float4*)w_pred)[sub * 2 + 1];
    float2 w2[4];
    w2[0] = make_float2(wA.x, wA.y); w2[1] = make_float2(wA.z, wA.w);
    w2[2] = make_float2(wB.x, wB.y); w2[3] = make_float2(wB.z, wB.w);
    const u32 lane_off = (u32)sub * 16;

    const int nQuads = (E + 3) >> 2;
    int q = waveId;
    if (q >= nQuads) return;

    // always-safe index load: edge id clamped to E-1
    auto ldidx = [&](int qq) -> int4 {
        int e = qq * 4 + g;
        e = (e < E) ? e : (E - 1);
        return idx4[e];
    };
    auto compute = [&](const uint4& sv, const uint4& iv,
                       const uint4& ca, const uint4& cb,
                       u32 mw, int qq) {
        const u32 su[4] = {sv.x, sv.y, sv.z, sv.w};
        const u32 iu[4] = {iv.x, iv.y, iv.z, iv.w};
        const u32 au[4] = {ca.x, ca.y, ca.z, ca.w};
        const u32 bu[4] = {cb.x, cb.y, cb.z, cb.w};
        const float2 one = make_float2(1.f, 1.f);
        float2 vacc = make_float2(0.f, 0.f);
#pragma unroll
        for (int j = 0; j < 4; ++j) {
            float2 A  = make_float2(bf2f_lo(au[j]), bf2f_hi(au[j]));
            float2 Sx = make_float2(bf2f_lo(su[j]), bf2f_hi(su[j]));
            float2 B  = make_float2(bf2f_lo(bu[j]), bf2f_hi(bu[j]));
            float2 Ix = make_float2(bf2f_lo(iu[j]), bf2f_hi(iu[j]));
            float2 ea = A * Sx;                    // v_pk_mul_f32
            float2 eb = B * Ix;
            float2 den = (ea + one) * (eb + one);  // (1+ea)(1+eb)
            float2 num = eb - ea;
            float2 rd = make_float2(__builtin_amdgcn_rcpf(den.x),
                                    __builtin_amdgcn_rcpf(den.y));
            vacc += (num * rd) * w2[j];
        }
        float v = vacc.x + vacc.y;
        v += __shfl_xor(v, 1, 64);
        v += __shfl_xor(v, 2, 64);
        v += __shfl_xor(v, 4, 64);
        v += __shfl_xor(v, 8, 64);
        if (sub == 0 && (qq * 4 + g) < E)
            atomicAdd((double*)((char*)sc + mw), (double)v + CNT_SCALE);
    };

#define GATH_S(I_, sv_, iv_) { \
        sv_ = *(const uint4*)((const char*)stu_p  + ((u32)(I_).x + lane_off)); \
        iv_ = *(const uint4*)((const char*)item_p + ((u32)(I_).y + lane_off)); }
#define GATH_C(I_, ca_, cb_) { \
        const char* cp_ = (const char*)conc_cat + ((u32)(I_).z + lane_off); \
        ca_ = *(const uint4*)cp_; cb_ = *(const uint4*)(cp_ + 256); }

    // Phase k: save mw, reload idx slot with I[k+3] (issued FIRST), gather
    // conc[k+1], gather stu/item[k+2], then compute S[k]/C[k]. The compiler's
    // FIFO vmcnt before compute leaves sv/iv[k+1], idx[k+3], conc[k+1],
    // sv/iv[k+2] in flight: 2 prefetch generations of table misses per wave.
#define STEP(SC, CC, IC, ICN1, ICN2, SF, CF) { \
        const u32 mw = (u32)IC.w; \
        IC = ldidx(q + 3 * S); \
        __builtin_amdgcn_sched_barrier(0); \
        GATH_C(ICN1, CF##a, CF##b); \
        GATH_S(ICN2, SF##s, SF##i); \
        __builtin_amdgcn_sched_barrier(0); \
        compute(SC##s, SC##i, CC##a, CC##b, mw, q); \
        q += S; \
        if (q >= nQuads) break; }

    // preamble: prime idx[0..2], conc[0], stu/item[0..1]
    int4 i0 = ldidx(q), i1 = ldidx(q + S), i2 = ldidx(q + 2 * S);
    uint4 s0s, s0i, s1s, s1i, s2s, s2i, c0a, c0b, c1a, c1b;
    GATH_C(i0, c0a, c0b);
    GATH_S(i0, s0s, s0i);
    GATH_S(i1, s1s, s1i);

    for (;;) {
        STEP(s0, c0, i0, i1, i2, s2, c1)   // k%6 == 0
        STEP(s1, c1, i1, i2, i0, s0, c0)   // k%6 == 1
        STEP(s2, c0, i2, i0, i1, s1, c1)   // k%6 == 2
        STEP(s0, c1, i0, i1, i2, s2, c0)   // k%6 == 3
        STEP(s1, c0, i1, i2, i0, s0, c1)   // k%6 == 4
        STEP(s2, c1, i2, i0, i1, s1, c0)   // k%6 == 5
    }
#undef STEP
#undef GATH_S
#undef GATH_C
}

__global__ __launch_bounds__(256) void final_kernel(
    const double* __restrict__ sc,
    const float* __restrict__ b_pred, float* __restrict__ out, int M)
{
    const int i = blockIdx.x * blockDim.x + threadIdx.x;
    if (i < M) {
        const double acc = sc[i];
        const double cnt = rint(acc * (1.0 / CNT_SCALE));   // |sum| << 2^23
        const double sum = acc - cnt * CNT_SCALE;
        const float mean = (float)(sum / fmax(cnt, 1.0));
        out[i] = sig_std(mean + b_pred[0]);
    }
}

extern "C" void kernel_launch(void* const* d_in, const int* in_sizes, int n_in,
                              void* d_out, int out_size, void* d_ws, size_t ws_size,
                              hipStream_t stream) {
    const float* stu_x    = (const float*)d_in[0];
    const float* item_x   = (const float*)d_in[1];
    const float* conc_x   = (const float*)d_in[2];
    const float* W_stu    = (const float*)d_in[3];
    const float* b_stu    = (const float*)d_in[4];
    const float* W_item   = (const float*)d_in[5];
    const float* b_item   = (const float*)d_in[6];
    const float* W_pred   = (const float*)d_in[7];
    const float* b_pred   = (const float*)d_in[8];
    const int* stu_track  = (const int*)d_in[9];
    const int* item_index = (const int*)d_in[10];
    const int* conc_index = (const int*)d_in[11];
    const int* mean_index = (const int*)d_in[12];

    const int NS = in_sizes[0] / CDIM;
    const int NI = in_sizes[1] / CDIM;
    const int NC = in_sizes[2] / CDIM;
    const int E  = in_sizes[9];
    const int M  = out_size;

    // workspace layout (all pieces 16B-aligned)
    double* sc     = (double*)d_ws;              // [M] packed (sum + cnt*2^24)
    u16* stu_p     = (u16*)(sc + M);
    u16* item_p    = stu_p  + (size_t)NS * CDIM;
    u16* conc_cat  = item_p + (size_t)NI * CDIM; // [NC][256]: exp2 stu | item side
    int4* idx4     = (int4*)(conc_cat + (size_t)NC * 256);

    const int nZero4 = (int)(((size_t)M * sizeof(double)) / 16);
    const int PB0 = (NS + 63) / 64, PB1 = (NI + 63) / 64, PB2 = (NC + 63) / 64;
    const int PBtot = PB0 + PB1 + 2 * PB2;

    fused_prep_proj<<<PBtot + PACK_BLOCKS, 256, 0, stream>>>(
        stu_x, item_x, conc_x, W_stu, W_item, b_stu, b_item,
        stu_p, item_p, conc_cat,
        (float4*)sc, nZero4,
        stu_track, item_index, conc_index, mean_index, idx4, E,
        NS, NI, NC);

    edge_kernel<<<2048, 256, 0, stream>>>(stu_p, item_p, conc_cat,
                                          idx4, W_pred, sc, E);

    final_kernel<<<(M + 255) / 256, 256, 0, stream>>>(sc, b_pred, (float*)d_out, M);
}

// Round 11
// 194.703 us; speedup vs baseline: 1.0002x; 1.0002x over previous
//
#include <hip/hip_runtime.h>

typedef unsigned short u16;
typedef unsigned int   u32;
typedef unsigned long long u64;

typedef short short8 __attribute__((ext_vector_type(8)));
typedef float floatx4 __attribute__((ext_vector_type(4)));

#define CDIM 128
#define K_NEG_LOG2E -1.4426950408889634f
#define CNT_SCALE 16777216.0   // 2^24: packs (sum, count) into one f64

// LDS weight tile: 128 rows x 136 u16 (272 B stride = 17*16 B).
#define WLDS_STRIDE 136
#define PACK_BLOCKS 512
// 8 stu-range bins (one per XCD). Capacity 1<<17 = 131072 >> E/8 + 18 sigma.
#define NBINS 8
#define BIN_CAP_SHIFT 17
#define BIN_CAP (1 << BIN_CAP_SHIFT)

__device__ __forceinline__ float bf2f_lo(u32 h) {
    union { u32 u; float f; } v; v.u = h << 16; return v.f;
}
__device__ __forceinline__ float bf2f_hi(u32 h) {
    union { u32 u; float f; } v; v.u = h & 0xffff0000u; return v.f;
}
__device__ __forceinline__ u16 f2bf(float f) {
    union { float f; u32 u; } v; v.f = f;
    u32 u = v.u;
    return (u16)((u + 0x7FFFu + ((u >> 16) & 1u)) >> 16);  // RNE
}
__device__ __forceinline__ float sig_std(float x) {
    return __builtin_amdgcn_rcpf(1.0f + __builtin_amdgcn_exp2f(x * K_NEG_LOG2E));
}

// One wave computes a 16-row tile from the LDS weight tile; stores
// exp2(proj + bias) in bf16.
__device__ __forceinline__ void proj_tile16_lds(
    const float* __restrict__ X, const u16* __restrict__ wlds,
    const float* __restrict__ bias, u16* __restrict__ out,
    int nrows, int ostride, int ooff, int row0, int lane)
{
    const int m = lane & 15;   // A-row / B-col / D-col
    const int g = lane >> 4;   // k-quad

    short8 a[4];
    {
        int arow = row0 + m;
        if (arow >= nrows) arow = nrows - 1;   // clamp; stores masked below
        const float* xrow = X + (size_t)arow * CDIM;
#pragma unroll
        for (int s = 0; s < 4; ++s) {
            float4 f0 = *(const float4*)(xrow + s * 32 + g * 8);
            float4 f1 = *(const float4*)(xrow + s * 32 + g * 8 + 4);
            a[s][0] = (short)f2bf(f0.x); a[s][1] = (short)f2bf(f0.y);
            a[s][2] = (short)f2bf(f0.z); a[s][3] = (short)f2bf(f0.w);
            a[s][4] = (short)f2bf(f1.x); a[s][5] = (short)f2bf(f1.y);
            a[s][6] = (short)f2bf(f1.z); a[s][7] = (short)f2bf(f1.w);
        }
    }

#pragma unroll
    for (int ct = 0; ct < 8; ++ct) {
        const u16* wrow = wlds + (size_t)(ct * 16 + m) * WLDS_STRIDE;
        floatx4 acc = {0.f, 0.f, 0.f, 0.f};
#pragma unroll
        for (int s = 0; s < 4; ++s) {
            short8 b = *(const short8*)(wrow + s * 32 + g * 8);
            acc = __builtin_amdgcn_mfma_f32_16x16x32_bf16(a[s], b, acc, 0, 0, 0);
        }
        const int col = ct * 16 + m;           // D: col = lane&15
        const float badd = bias ? bias[col] * K_NEG_LOG2E : 0.f;
#pragma unroll
        for (int i = 0; i < 4; ++i) {
            int r = row0 + g * 4 + i;          // D: row = (lane>>4)*4 + reg
            if (r < nrows)
                out[(size_t)r * ostride + ooff + col] =
                    f2bf(__builtin_amdgcn_exp2f(acc[i] + badd));
        }
    }
}

// ONE launch replacing prep+proj. Block roles:
//   [0, PACK_BLOCKS): zero f64 accumulators + BINNED edge-index scatter
//     (8 stu-range bins, wave-ballot ranking: 1 LDS atomic/wave/bin,
//      1 global reservation/block/bin — not R3's 1M per-thread atomics).
//   [PACK_BLOCKS, PACK_BLOCKS+PBtot): projection blocks.
__global__ __launch_bounds__(256) void fused_prep_proj(
    const float* __restrict__ stu_x, const float* __restrict__ item_x,
    const float* __restrict__ conc_x,
    const float* __restrict__ Wstu, const float* __restrict__ Witem,
    const float* __restrict__ b_stu, const float* __restrict__ b_item,
    u16* __restrict__ stu_p, u16* __restrict__ item_p, u16* __restrict__ conc_cat,
    float4* __restrict__ zero4, int nZero4,
    const int* __restrict__ stu_track, const int* __restrict__ item_index,
    const int* __restrict__ conc_index, const int* __restrict__ mean_index,
    int4* __restrict__ idx4, int* __restrict__ cursor, u32 MAGIC, int E,
    int NS, int NI, int NC)
{
    __shared__ u16 wlds[128 * WLDS_STRIDE];

    const int PB0 = (NS + 63) / 64, PB1 = (NI + 63) / 64, PB2 = (NC + 63) / 64;
    const int PBtot = PB0 + PB1 + 2 * PB2;
    int b = blockIdx.x;

    if (b < PACK_BLOCKS) {
        // ---- pack/zero role (runs first so idx4 is ready early) ----
        const int tid = threadIdx.x;
        const int lane = tid & 63;
        {
            const float4 z = {0.f, 0.f, 0.f, 0.f};
            for (int i = b * 256 + tid; i < nZero4; i += PACK_BLOCKS * 256)
                zero4[i] = z;
        }
        __shared__ int lhist[NBINS], lbase[NBINS], lcur[NBINS];
        const int CH = (E + PACK_BLOCKS - 1) / PACK_BLOCKS;
        const int e0 = b * CH;
        const int e1 = min(E, e0 + CH);
        if (tid < NBINS) { lhist[tid] = 0; lcur[tid] = 0; }
        __syncthreads();

        // Phase A: per-block bin histogram via wave-ballot counts
        for (int base = e0; base < e1; base += 256) {
            const int e = base + tid;
            const bool valid = e < e1;
            u32 binv = 0;
            if (valid)
                binv = min((u32)(((u64)(u32)stu_track[e] * MAGIC) >> 32),
                           (u32)(NBINS - 1));
            const u64 am = __ballot(valid);
            const u64 b0 = __ballot((binv & 1) != 0);
            const u64 b1 = __ballot((binv & 2) != 0);
            const u64 b2 = __ballot((binv & 4) != 0);
            const u64 same = am
                & ((binv & 1) ? b0 : ~b0)
                & ((binv & 2) ? b1 : ~b1)
                & ((binv & 4) ? b2 : ~b2);
            const u32 rank = (u32)__popcll(same & ((1ull << lane) - 1ull));
            if (valid && rank == 0)
                atomicAdd(&lhist[binv], (int)__popcll(same));
        }
        __syncthreads();
        if (tid < NBINS) lbase[tid] = atomicAdd(&cursor[tid], lhist[tid]);
        __syncthreads();

        // Phase B: scatter records to bin regions (intra-wave ballot rank)
        for (int base = e0; base < e1; base += 256) {
            const int e = base + tid;
            const bool valid = e < e1;
            int st = 0, it = 0, cc = 0, mi = 0;
            u32 binv = 0;
            if (valid) {
                st = stu_track[e]; it = item_index[e];
                cc = conc_index[e]; mi = mean_index[e];
                binv = min((u32)(((u64)(u32)st * MAGIC) >> 32),
                           (u32)(NBINS - 1));
            }
            const u64 am = __ballot(valid);
            const u64 b0 = __ballot((binv & 1) != 0);
            const u64 b1 = __ballot((binv & 2) != 0);
            const u64 b2 = __ballot((binv & 4) != 0);
            const u64 same = am
                & ((binv & 1) ? b0 : ~b0)
                & ((binv & 2) ? b1 : ~b1)
                & ((binv & 4) ? b2 : ~b2);
            const u32 rank = (u32)__popcll(same & ((1ull << lane) - 1ull));
            int wbase = 0;
            if (valid && rank == 0)
                wbase = atomicAdd(&lcur[binv], (int)__popcll(same));
            int leadLane = (int)__ffsll((long long)same) - 1;
            if (leadLane < 0) leadLane = 0;
            wbase = __shfl(wbase, leadLane, 64);
            if (valid) {
                const int p = lbase[binv] + wbase + (int)rank;
                if (p < BIN_CAP) {
                    int4 t;
                    t.x = st << 8;   // 256 B rows
                    t.y = it << 8;   // 256 B rows
                    t.z = cc << 9;   // 512 B rows (cat)
                    t.w = mi << 3;   // f64 slots
                    idx4[((size_t)binv << BIN_CAP_SHIFT) + p] = t;
                }
            }
        }
        return;
    }
    b -= PACK_BLOCKS;
    if (b >= PBtot) return;

    // ---- projection role: segment select (block-uniform) ----
    const float* X; const float* Wsel; const float* bias;
    u16* out; int nrows, ostride, ooff, base;
    if (b < PB0)      { X = stu_x;  Wsel = Wstu;  bias = nullptr; out = stu_p;
                        nrows = NS; ostride = 128; ooff = 0;   base = b * 64; }
    else if ((b -= PB0) < PB1)
                      { X = item_x; Wsel = Witem; bias = nullptr; out = item_p;
                        nrows = NI; ostride = 128; ooff = 0;   base = b * 64; }
    else if ((b -= PB1) < PB2)
                      { X = conc_x; Wsel = Wstu;  bias = b_stu;  out = conc_cat;
                        nrows = NC; ostride = 256; ooff = 0;   base = b * 64; }
    else              { b -= PB2;
                        X = conc_x; Wsel = Witem; bias = b_item; out = conc_cat;
                        nrows = NC; ostride = 256; ooff = 128; base = b * 64; }

    // convert this block's W (f32 -> pre-scaled bf16) into LDS
    {
        const int t   = threadIdx.x;
        const int col = t >> 1;
        const int k0  = (t & 1) * 64;
        const float4* src = (const float4*)(Wsel + col * 128 + k0);
        u32* dst = (u32*)(wlds + col * WLDS_STRIDE + k0);
#pragma unroll
        for (int i = 0; i < 16; ++i) {
            float4 f = src[i];
            dst[2 * i]     = (u32)f2bf(f.x * K_NEG_LOG2E) |
                             ((u32)f2bf(f.y * K_NEG_LOG2E) << 16);
            dst[2 * i + 1] = (u32)f2bf(f.z * K_NEG_LOG2E) |
                             ((u32)f2bf(f.w * K_NEG_LOG2E) << 16);
        }
    }
    __syncthreads();

    const int lane = threadIdx.x & 63;
    const int row0 = base + (threadIdx.x >> 6) * 16;
    if (row0 < nrows)
        proj_tile16_lds(X, wlds, bias, out, nrows, ostride, ooff, row0, lane);
}

// 16 lanes per edge, 4 edges per wave. R8's proven depth-2 stu/item,
// depth-1 conc, depth-3 idx pipeline — now per stu-range bin.
// bin = blockIdx.x & 7: under round-robin block->XCD dispatch, all blocks
// of bin x run on XCD x, whose L2 (4 MB) then serves that bin's 1.6 MB
// stu-table slice as hits instead of L3/HBM re-fetches (204 MB FETCH at
// R8 = L2-capacity refetch of the 12.8 MB stu table, 0.36 us/MB slope
// measured in R7).
__global__ __launch_bounds__(256) void edge_kernel(
    const u16* __restrict__ stu_p, const u16* __restrict__ item_p,
    const u16* __restrict__ conc_cat,
    const int4* __restrict__ idx4,     // binned byte-offset records
    const int* __restrict__ cursor,    // per-bin edge counts
    const float* __restrict__ w_pred,
    double* __restrict__ sc)
{
    const int lane = threadIdx.x & 63;
    const int sub  = lane & 15;      // position within edge
    const int g    = lane >> 4;      // edge within quad

    const int bin = blockIdx.x & (NBINS - 1);
    const int cnt = min(cursor[bin], BIN_CAP);
    if (cnt <= 0) return;
    const int4* __restrict__ idxr = idx4 + ((size_t)bin << BIN_CAP_SHIFT);

    // wave id / stride within this bin
    const int wv = (int)((blockIdx.x >> 3) * (blockDim.x >> 6) + (threadIdx.x >> 6));
    const int S  = (int)((gridDim.x >> 3) * (blockDim.x >> 6));

    const float4 wA = ((const float4*)w_pred)[sub * 2];
    const float4 wB = ((const float4*)w_pred)[sub * 2 + 1];
    float2 w2[4];
    w2[0] = make_float2(wA.x, wA.y); w2[1] = make_float2(wA.z, wA.w);
    w2[2] = make_float2(wB.x, wB.y); w2[3] = make_float2(wB.z, wB.w);
    const u32 lane_off = (u32)sub * 16;

    const int nQuads = (cnt + 3) >> 2;
    int q = wv;
    if (q >= nQuads) return;

    // always-safe index load: edge id clamped to cnt-1
    auto ldidx = [&](int qq) -> int4 {
        int e = qq * 4 + g;
        e = (e < cnt) ? e : (cnt - 1);
        return idxr[e];
    };
    auto compute = [&](const uint4& sv, const uint4& iv,
                       const uint4& ca, const uint4& cb,
                       u32 mw, int qq) {
        const u32 su[4] = {sv.x, sv.y, sv.z, sv.w};
        const u32 iu[4] = {iv.x, iv.y, iv.z, iv.w};
        const u32 au[4] = {ca.x, ca.y, ca.z, ca.w};
        const u32 bu[4] = {cb.x, cb.y, cb.z, cb.w};
        const float2 one = make_float2(1.f, 1.f);
        float2 vacc = make_float2(0.f, 0.f);
#pragma unroll
        for (int j = 0; j < 4; ++j) {
            float2 A  = make_float2(bf2f_lo(au[j]), bf2f_hi(au[j]));
            float2 Sx = make_float2(bf2f_lo(su[j]), bf2f_hi(su[j]));
            float2 B  = make_float2(bf2f_lo(bu[j]), bf2f_hi(bu[j]));
            float2 Ix = make_float2(bf2f_lo(iu[j]), bf2f_hi(iu[j]));
            float2 ea = A * Sx;                    // v_pk_mul_f32
            float2 eb = B * Ix;
            float2 den = (ea + one) * (eb + one);  // (1+ea)(1+eb)
            float2 num = eb - ea;
            float2 rd = make_float2(__builtin_amdgcn_rcpf(den.x),
                                    __builtin_amdgcn_rcpf(den.y));
            vacc += (num * rd) * w2[j];
        }
        float v = vacc.x + vacc.y;
        v += __shfl_xor(v, 1, 64);
        v += __shfl_xor(v, 2, 64);
        v += __shfl_xor(v, 4, 64);
        v += __shfl_xor(v, 8, 64);
        if (sub == 0 && (qq * 4 + g) < cnt)
            atomicAdd((double*)((char*)sc + mw), (double)v + CNT_SCALE);
    };

#define GATH_S(I_, sv_, iv_) { \
        sv_ = *(const uint4*)((const char*)stu_p  + ((u32)(I_).x + lane_off)); \
        iv_ = *(const uint4*)((const char*)item_p + ((u32)(I_).y + lane_off)); }
#define GATH_C(I_, ca_, cb_) { \
        const char* cp_ = (const char*)conc_cat + ((u32)(I_).z + lane_off); \
        ca_ = *(const uint4*)cp_; cb_ = *(const uint4*)(cp_ + 256); }

#define STEP(SC, CC, IC, ICN1, ICN2, SF, CF) { \
        const u32 mw = (u32)IC.w; \
        IC = ldidx(q + 3 * S); \
        __builtin_amdgcn_sched_barrier(0); \
        GATH_C(ICN1, CF##a, CF##b); \
        GATH_S(ICN2, SF##s, SF##i); \
        __builtin_amdgcn_sched_barrier(0); \
        compute(SC##s, SC##i, CC##a, CC##b, mw, q); \
        q += S; \
        if (q >= nQuads) break; }

    // preamble: prime idx[0..2], conc[0], stu/item[0..1]
    int4 i0 = ldidx(q), i1 = ldidx(q + S), i2 = ldidx(q + 2 * S);
    uint4 s0s, s0i, s1s, s1i, s2s, s2i, c0a, c0b, c1a, c1b;
    GATH_C(i0, c0a, c0b);
    GATH_S(i0, s0s, s0i);
    GATH_S(i1, s1s, s1i);

    for (;;) {
        STEP(s0, c0, i0, i1, i2, s2, c1)   // k%6 == 0
        STEP(s1, c1, i1, i2, i0, s0, c0)   // k%6 == 1
        STEP(s2, c0, i2, i0, i1, s1, c1)   // k%6 == 2
        STEP(s0, c1, i0, i1, i2, s2, c0)   // k%6 == 3
        STEP(s1, c0, i1, i2, i0, s0, c1)   // k%6 == 4
        STEP(s2, c1, i2, i0, i1, s1, c0)   // k%6 == 5
    }
#undef STEP
#undef GATH_S
#undef GATH_C
}

__global__ __launch_bounds__(256) void final_kernel(
    const double* __restrict__ sc,
    const float* __restrict__ b_pred, float* __restrict__ out, int M)
{
    const int i = blockIdx.x * blockDim.x + threadIdx.x;
    if (i < M) {
        const double acc = sc[i];
        const double cnt = rint(acc * (1.0 / CNT_SCALE));   // |sum| << 2^23
        const double sum = acc - cnt * CNT_SCALE;
        const float mean = (float)(sum / fmax(cnt, 1.0));
        out[i] = sig_std(mean + b_pred[0]);
    }
}

extern "C" void kernel_launch(void* const* d_in, const int* in_sizes, int n_in,
                              void* d_out, int out_size, void* d_ws, size_t ws_size,
                              hipStream_t stream) {
    const float* stu_x    = (const float*)d_in[0];
    const float* item_x   = (const float*)d_in[1];
    const float* conc_x   = (const float*)d_in[2];
    const float* W_stu    = (const float*)d_in[3];
    const float* b_stu    = (const float*)d_in[4];
    const float* W_item   = (const float*)d_in[5];
    const float* b_item   = (const float*)d_in[6];
    const float* W_pred   = (const float*)d_in[7];
    const float* b_pred   = (const float*)d_in[8];
    const int* stu_track  = (const int*)d_in[9];
    const int* item_index = (const int*)d_in[10];
    const int* conc_index = (const int*)d_in[11];
    const int* mean_index = (const int*)d_in[12];

    const int NS = in_sizes[0] / CDIM;
    const int NI = in_sizes[1] / CDIM;
    const int NC = in_sizes[2] / CDIM;
    const int E  = in_sizes[9];
    const int M  = out_size;

    // workspace layout (all pieces 16B-aligned)
    double* sc     = (double*)d_ws;              // [M] packed (sum + cnt*2^24)
    u16* stu_p     = (u16*)(sc + M);
    u16* item_p    = stu_p  + (size_t)NS * CDIM;
    u16* conc_cat  = item_p + (size_t)NI * CDIM; // [NC][256]: exp2 stu | item side
    int4* idx4     = (int4*)(conc_cat + (size_t)NC * 256);  // NBINS*BIN_CAP records
    int*  cursor   = (int*)(idx4 + ((size_t)NBINS << BIN_CAP_SHIFT));

    hipMemsetAsync(cursor, 0, NBINS * sizeof(int), stream);

    // bin = floor(stu * NBINS / NS) via umulhi magic (consistent everywhere)
    const u32 MAGIC = (u32)((((u64)NBINS << 32) + (u64)NS - 1) / (u64)NS);

    const int nZero4 = (int)(((size_t)M * sizeof(double)) / 16);
    const int PB0 = (NS + 63) / 64, PB1 = (NI + 63) / 64, PB2 = (NC + 63) / 64;
    const int PBtot = PB0 + PB1 + 2 * PB2;

    fused_prep_proj<<<PACK_BLOCKS + PBtot, 256, 0, stream>>>(
        stu_x, item_x, conc_x, W_stu, W_item, b_stu, b_item,
        stu_p, item_p, conc_cat,
        (float4*)sc, nZero4,
        stu_track, item_index, conc_index, mean_index, idx4, cursor, MAGIC, E,
        NS, NI, NC);

    edge_kernel<<<4096, 256, 0, stream>>>(stu_p, item_p, conc_cat,
                                          idx4, cursor, W_pred, sc);

    final_kernel<<<(M + 255) / 256, 256, 0, stream>>>(sc, b_pred, (float*)d_out, M);
}

// Round 13
// 190.381 us; speedup vs baseline: 1.0229x; 1.0227x over previous
//
#include <hip/hip_runtime.h>

typedef unsigned short u16;
typedef unsigned int   u32;

typedef short short8 __attribute__((ext_vector_type(8)));
typedef float floatx4 __attribute__((ext_vector_type(4)));

#define CDIM 128
#define K_NEG_LOG2E -1.4426950408889634f
#define CNT_SCALE 16777216.0   // 2^24: packs (sum, count) into one f64

// LDS weight tile: 128 rows x 136 u16 (272 B stride = 17*16 B).
#define WLDS_STRIDE 136
#define PACK_BLOCKS 512

__device__ __forceinline__ float bf2f_lo(u32 h) {
    union { u32 u; float f; } v; v.u = h << 16; return v.f;
}
__device__ __forceinline__ float bf2f_hi(u32 h) {
    union { u32 u; float f; } v; v.u = h & 0xffff0000u; return v.f;
}
__device__ __forceinline__ u16 f2bf(float f) {
    union { float f; u32 u; } v; v.f = f;
    u32 u = v.u;
    return (u16)((u + 0x7FFFu + ((u >> 16) & 1u)) >> 16);  // RNE
}
__device__ __forceinline__ float sig_std(float x) {
    return __builtin_amdgcn_rcpf(1.0f + __builtin_amdgcn_exp2f(x * K_NEG_LOG2E));
}

// One wave computes a 16-row tile from the LDS weight tile; stores
// exp2(proj + bias) in bf16.
__device__ __forceinline__ void proj_tile16_lds(
    const float* __restrict__ X, const u16* __restrict__ wlds,
    const float* __restrict__ bias, u16* __restrict__ out,
    int nrows, int ostride, int ooff, int row0, int lane)
{
    const int m = lane & 15;   // A-row / B-col / D-col
    const int g = lane >> 4;   // k-quad

    short8 a[4];
    {
        int arow = row0 + m;
        if (arow >= nrows) arow = nrows - 1;   // clamp; stores masked below
        const float* xrow = X + (size_t)arow * CDIM;
#pragma unroll
        for (int s = 0; s < 4; ++s) {
            float4 f0 = *(const float4*)(xrow + s * 32 + g * 8);
            float4 f1 = *(const float4*)(xrow + s * 32 + g * 8 + 4);
            a[s][0] = (short)f2bf(f0.x); a[s][1] = (short)f2bf(f0.y);
            a[s][2] = (short)f2bf(f0.z); a[s][3] = (short)f2bf(f0.w);
            a[s][4] = (short)f2bf(f1.x); a[s][5] = (short)f2bf(f1.y);
            a[s][6] = (short)f2bf(f1.z); a[s][7] = (short)f2bf(f1.w);
        }
    }

#pragma unroll
    for (int ct = 0; ct < 8; ++ct) {
        const u16* wrow = wlds + (size_t)(ct * 16 + m) * WLDS_STRIDE;
        floatx4 acc = {0.f, 0.f, 0.f, 0.f};
#pragma unroll
        for (int s = 0; s < 4; ++s) {
            short8 b = *(const short8*)(wrow + s * 32 + g * 8);
            acc = __builtin_amdgcn_mfma_f32_16x16x32_bf16(a[s], b, acc, 0, 0, 0);
        }
        const int col = ct * 16 + m;           // D: col = lane&15
        const float badd = bias ? bias[col] * K_NEG_LOG2E : 0.f;
#pragma unroll
        for (int i = 0; i < 4; ++i) {
            int r = row0 + g * 4 + i;          // D: row = (lane>>4)*4 + reg
            if (r < nrows)
                out[(size_t)r * ostride + ooff + col] =
                    f2bf(__builtin_amdgcn_exp2f(acc[i] + badd));
        }
    }
}

// ONE launch replacing prep+proj. Block roles (pack blocks FIRST — R10's
// measured-no-worse ordering):
//   [0, PACK_BLOCKS): zero f64 accumulators + pack edge indices (linear).
//   [PACK_BLOCKS, PACK_BLOCKS+PBtot): projection blocks.
__global__ __launch_bounds__(256) void fused_prep_proj(
    const float* __restrict__ stu_x, const float* __restrict__ item_x,
    const float* __restrict__ conc_x,
    const float* __restrict__ Wstu, const float* __restrict__ Witem,
    const float* __restrict__ b_stu, const float* __restrict__ b_item,
    u16* __restrict__ stu_p, u16* __restrict__ item_p, u16* __restrict__ conc_cat,
    float4* __restrict__ zero4, int nZero4,
    const int* __restrict__ stu_track, const int* __restrict__ item_index,
    const int* __restrict__ conc_index, const int* __restrict__ mean_index,
    int4* __restrict__ idx4, int E,
    int NS, int NI, int NC)
{
    __shared__ u16 wlds[128 * WLDS_STRIDE];

    const int PB0 = (NS + 63) / 64, PB1 = (NI + 63) / 64, PB2 = (NC + 63) / 64;
    const int PBtot = PB0 + PB1 + 2 * PB2;
    int b = blockIdx.x;

    if (b < PACK_BLOCKS) {
        // ---- pack/zero role ----
        const int tid = b * 256 + threadIdx.x;
        const int stride = PACK_BLOCKS * 256;
        const float4 z = {0.f, 0.f, 0.f, 0.f};
        for (int i = tid; i < nZero4; i += stride) zero4[i] = z;
        for (int e = tid; e < E; e += stride) {
            int4 t;
            t.x = stu_track[e]  << 8;   // 256 B rows
            t.y = item_index[e] << 8;   // 256 B rows
            t.z = conc_index[e] << 9;   // 512 B rows (cat)
            t.w = mean_index[e] << 3;   // f64 slots
            idx4[e] = t;
        }
        return;
    }
    b -= PACK_BLOCKS;
    if (b >= PBtot) return;

    // ---- projection role: segment select (block-uniform) ----
    const float* X; const float* Wsel; const float* bias;
    u16* out; int nrows, ostride, ooff, base;
    if (b < PB0)      { X = stu_x;  Wsel = Wstu;  bias = nullptr; out = stu_p;
                        nrows = NS; ostride = 128; ooff = 0;   base = b * 64; }
    else if ((b -= PB0) < PB1)
                      { X = item_x; Wsel = Witem; bias = nullptr; out = item_p;
                        nrows = NI; ostride = 128; ooff = 0;   base = b * 64; }
    else if ((b -= PB1) < PB2)
                      { X = conc_x; Wsel = Wstu;  bias = b_stu;  out = conc_cat;
                        nrows = NC; ostride = 256; ooff = 0;   base = b * 64; }
    else              { b -= PB2;
                        X = conc_x; Wsel = Witem; bias = b_item; out = conc_cat;
                        nrows = NC; ostride = 256; ooff = 128; base = b * 64; }

    // convert this block's W (f32 -> pre-scaled bf16) into LDS
    {
        const int t   = threadIdx.x;
        const int col = t >> 1;
        const int k0  = (t & 1) * 64;
        const float4* src = (const float4*)(Wsel + col * 128 + k0);
        u32* dst = (u32*)(wlds + col * WLDS_STRIDE + k0);
#pragma unroll
        for (int i = 0; i < 16; ++i) {
            float4 f = src[i];
            dst[2 * i]     = (u32)f2bf(f.x * K_NEG_LOG2E) |
                             ((u32)f2bf(f.y * K_NEG_LOG2E) << 16);
            dst[2 * i + 1] = (u32)f2bf(f.z * K_NEG_LOG2E) |
                             ((u32)f2bf(f.w * K_NEG_LOG2E) << 16);
        }
    }
    __syncthreads();

    const int lane = threadIdx.x & 63;
    const int row0 = base + (threadIdx.x >> 6) * 16;
    if (row0 < nrows)
        proj_tile16_lds(X, wlds, bias, out, nrows, ostride, ooff, row0, lane);
}

// 16 lanes per edge, 4 edges per wave. R8 session-best structure verbatim
// (edge 70.2 us @ total 192.6): depth-2 stu/item, depth-1 conc, depth-3 idx
// issued FIRST each phase, 4096 blocks. Findings locked in from R0-R10:
//  - MLP depth 2 at full grid: +5 us (R8 win)
//  - traffic reduction (conc->LDS, stu->XCD-L2): FETCH -45% but time null
//    -> latency/issue-balanced, not BW-bound at any cache level
//  - VALU floor ~38 us (55% busy); stall remainder robust to 8 probes
__global__ __launch_bounds__(256) void edge_kernel(
    const u16* __restrict__ stu_p, const u16* __restrict__ item_p,
    const u16* __restrict__ conc_cat,
    const int4* __restrict__ idx4,     // byte offsets {stu, item, conc, mean}
    const float* __restrict__ w_pred,
    double* __restrict__ sc, int E)
{
    const int lane = threadIdx.x & 63;
    const int sub  = lane & 15;      // position within edge
    const int g    = lane >> 4;      // edge within quad
    const int waveId = (int)((blockIdx.x * blockDim.x + threadIdx.x) >> 6);
    const int S      = (int)((gridDim.x * blockDim.x) >> 6);   // wave stride

    const float4 wA = ((const float4*)w_pred)[sub * 2];
    const float4 wB = ((const float4*)w_pred)[sub * 2 + 1];
    float2 w2[4];
    w2[0] = make_float2(wA.x, wA.y); w2[1] = make_float2(wA.z, wA.w);
    w2[2] = make_float2(wB.x, wB.y); w2[3] = make_float2(wB.z, wB.w);
    const u32 lane_off = (u32)sub * 16;

    const int nQuads = (E + 3) >> 2;
    int q = waveId;
    if (q >= nQuads) return;

    // always-safe index load: edge id clamped to E-1
    auto ldidx = [&](int qq) -> int4 {
        int e = qq * 4 + g;
        e = (e < E) ? e : (E - 1);
        return idx4[e];
    };
    auto compute = [&](const uint4& sv, const uint4& iv,
                       const uint4& ca, const uint4& cb,
                       u32 mw, int qq) {
        const u32 su[4] = {sv.x, sv.y, sv.z, sv.w};
        const u32 iu[4] = {iv.x, iv.y, iv.z, iv.w};
        const u32 au[4] = {ca.x, ca.y, ca.z, ca.w};
        const u32 bu[4] = {cb.x, cb.y, cb.z, cb.w};
        const float2 one = make_float2(1.f, 1.f);
        float2 vacc = make_float2(0.f, 0.f);
#pragma unroll
        for (int j = 0; j < 4; ++j) {
            float2 A  = make_float2(bf2f_lo(au[j]), bf2f_hi(au[j]));
            float2 Sx = make_float2(bf2f_lo(su[j]), bf2f_hi(su[j]));
            float2 B  = make_float2(bf2f_lo(bu[j]), bf2f_hi(bu[j]));
            float2 Ix = make_float2(bf2f_lo(iu[j]), bf2f_hi(iu[j]));
            float2 ea = A * Sx;                    // v_pk_mul_f32
            float2 eb = B * Ix;
            float2 den = (ea + one) * (eb + one);  // (1+ea)(1+eb)
            float2 num = eb - ea;
            float2 rd = make_float2(__builtin_amdgcn_rcpf(den.x),
                                    __builtin_amdgcn_rcpf(den.y));
            vacc += (num * rd) * w2[j];
        }
        float v = vacc.x + vacc.y;
        v += __shfl_xor(v, 1, 64);
        v += __shfl_xor(v, 2, 64);
        v += __shfl_xor(v, 4, 64);
        v += __shfl_xor(v, 8, 64);
        if (sub == 0 && (qq * 4 + g) < E)
            atomicAdd((double*)((char*)sc + mw), (double)v + CNT_SCALE);
    };

#define GATH_S(I_, sv_, iv_) { \
        sv_ = *(const uint4*)((const char*)stu_p  + ((u32)(I_).x + lane_off)); \
        iv_ = *(const uint4*)((const char*)item_p + ((u32)(I_).y + lane_off)); }
#define GATH_C(I_, ca_, cb_) { \
        const char* cp_ = (const char*)conc_cat + ((u32)(I_).z + lane_off); \
        ca_ = *(const uint4*)cp_; cb_ = *(const uint4*)(cp_ + 256); }

    // Phase k: save mw, reload idx slot with I[k+3] (issued FIRST), gather
    // conc[k+1], gather stu/item[k+2], then compute S[k]/C[k]. The compiler's
    // FIFO vmcnt before compute leaves sv/iv[k+1], idx[k+3], conc[k+1],
    // sv/iv[k+2] in flight: 2 prefetch generations of table misses per wave.
#define STEP(SC, CC, IC, ICN1, ICN2, SF, CF) { \
        const u32 mw = (u32)IC.w; \
        IC = ldidx(q + 3 * S); \
        __builtin_amdgcn_sched_barrier(0); \
        GATH_C(ICN1, CF##a, CF##b); \
        GATH_S(ICN2, SF##s, SF##i); \
        __builtin_amdgcn_sched_barrier(0); \
        compute(SC##s, SC##i, CC##a, CC##b, mw, q); \
        q += S; \
        if (q >= nQuads) break; }

    // preamble: prime idx[0..2], conc[0], stu/item[0..1]
    int4 i0 = ldidx(q), i1 = ldidx(q + S), i2 = ldidx(q + 2 * S);
    uint4 s0s, s0i, s1s, s1i, s2s, s2i, c0a, c0b, c1a, c1b;
    GATH_C(i0, c0a, c0b);
    GATH_S(i0, s0s, s0i);
    GATH_S(i1, s1s, s1i);

    for (;;) {
        STEP(s0, c0, i0, i1, i2, s2, c1)   // k%6 == 0
        STEP(s1, c1, i1, i2, i0, s0, c0)   // k%6 == 1
        STEP(s2, c0, i2, i0, i1, s1, c1)   // k%6 == 2
        STEP(s0, c1, i0, i1, i2, s2, c0)   // k%6 == 3
        STEP(s1, c0, i1, i2, i0, s0, c1)   // k%6 == 4
        STEP(s2, c1, i2, i0, i1, s1, c0)   // k%6 == 5
    }
#undef STEP
#undef GATH_S
#undef GATH_C
}

__global__ __launch_bounds__(256) void final_kernel(
    const double* __restrict__ sc,
    const float* __restrict__ b_pred, float* __restrict__ out, int M)
{
    const int i = blockIdx.x * blockDim.x + threadIdx.x;
    if (i < M) {
        const double acc = sc[i];
        const double cnt = rint(acc * (1.0 / CNT_SCALE));   // |sum| << 2^23
        const double sum = acc - cnt * CNT_SCALE;
        const float mean = (float)(sum / fmax(cnt, 1.0));
        out[i] = sig_std(mean + b_pred[0]);
    }
}

extern "C" void kernel_launch(void* const* d_in, const int* in_sizes, int n_in,
                              void* d_out, int out_size, void* d_ws, size_t ws_size,
                              hipStream_t stream) {
    const float* stu_x    = (const float*)d_in[0];
    const float* item_x   = (const float*)d_in[1];
    const float* conc_x   = (const float*)d_in[2];
    const float* W_stu    = (const float*)d_in[3];
    const float* b_stu    = (const float*)d_in[4];
    const float* W_item   = (const float*)d_in[5];
    const float* b_item   = (const float*)d_in[6];
    const float* W_pred   = (const float*)d_in[7];
    const float* b_pred   = (const float*)d_in[8];
    const int* stu_track  = (const int*)d_in[9];
    const int* item_index = (const int*)d_in[10];
    const int* conc_index = (const int*)d_in[11];
    const int* mean_index = (const int*)d_in[12];

    const int NS = in_sizes[0] / CDIM;
    const int NI = in_sizes[1] / CDIM;
    const int NC = in_sizes[2] / CDIM;
    const int E  = in_sizes[9];
    const int M  = out_size;

    // workspace layout (all pieces 16B-aligned)
    double* sc     = (double*)d_ws;              // [M] packed (sum + cnt*2^24)
    u16* stu_p     = (u16*)(sc + M);
    u16* item_p    = stu_p  + (size_t)NS * CDIM;
    u16* conc_cat  = item_p + (size_t)NI * CDIM; // [NC][256]: exp2 stu | item side
    int4* idx4     = (int4*)(conc_cat + (size_t)NC * 256);

    const int nZero4 = (int)(((size_t)M * sizeof(double)) / 16);
    const int PB0 = (NS + 63) / 64, PB1 = (NI + 63) / 64, PB2 = (NC + 63) / 64;
    const int PBtot = PB0 + PB1 + 2 * PB2;

    fused_prep_proj<<<PACK_BLOCKS + PBtot, 256, 0, stream>>>(
        stu_x, item_x, conc_x, W_stu, W_item, b_stu, b_item,
        stu_p, item_p, conc_cat,
        (float4*)sc, nZero4,
        stu_track, item_index, conc_index, mean_index, idx4, E,
        NS, NI, NC);

    edge_kernel<<<4096, 256, 0, stream>>>(stu_p, item_p, conc_cat,
                                          idx4, W_pred, sc, E);

    final_kernel<<<(M + 255) / 256, 256, 0, stream>>>(sc, b_pred, (float*)d_out, M);
}